// Round 3
// baseline (105.623 us; speedup 1.0000x reference)
//
#include <hip/hip_runtime.h>
#include <hip/hip_fp16.h>
#include <math.h>

// u_dot_v + sigmoid, D=64.
// R2: fp16 table in d_ws, 8 lanes/edge.                              [89.7 us]
// R3/R4: 4 edges per 8-lane group, 8 gathers in flight (MLP x3).     [84.8 us]
//   Post-mortem: -5 us only. Profile shows 268 MB ws-poison fills at ~46 us;
//   both our kernels < 44.6 us; 46(fill) + 4(conv) + ~35(dot) = 85 = dur.
//   => dominant cost is the workspace re-poison attached to d_ws use.
// R5: DIAGNOSTIC + likely win: workspace-free. Single kernel, gather f32
//   rows directly from h (no conversion, no d_ws). Keep MLP structure:
//   4 edges per 16-lane group, 8 independent float4 gathers in flight,
//   int4 broadcast index loads, float4 nontemporal output.
//   If fill was ws-conditional -> total ~35-50 us. If not -> revert fp16.

#define DOT_D 64

typedef int   v4i __attribute__((ext_vector_type(4)));
typedef float v4f __attribute__((ext_vector_type(4)));

// 4 edges per 16-lane group; 8 gathers (float4) in flight per thread.
__global__ __launch_bounds__(256) void dot_sigmoid_f32_mlp_kernel(
    const float* __restrict__ h,
    const int* __restrict__ src,
    const int* __restrict__ dst,
    float* __restrict__ out,
    int E)
{
    int tid  = blockIdx.x * blockDim.x + threadIdx.x;
    int lane = tid & 15;    // 16 lanes per edge-group (16 B/lane = 256 B row)
    int g    = tid >> 4;    // group id: edges 4g .. 4g+3
    int eb   = g << 2;
    if (eb >= E) return;

    if (eb + 3 < E) {
        // Coalesced broadcast index loads: all 16 lanes read the same 16 B.
        v4i s4 = __builtin_nontemporal_load((const v4i*)(src + eb));
        v4i d4 = __builtin_nontemporal_load((const v4i*)(dst + eb));
        int ss[4] = { s4.x, s4.y, s4.z, s4.w };
        int dd[4] = { d4.x, d4.y, d4.z, d4.w };

        // Issue all 8 independent gathers (16 B/lane, 2 lines per 256 B row).
        float4 ur[4], vr[4];
#pragma unroll
        for (int i = 0; i < 4; ++i) {
            ur[i] = ((const float4*)(h + (size_t)ss[i] * DOT_D))[lane];
            vr[i] = ((const float4*)(h + (size_t)dd[i] * DOT_D))[lane];
        }

        v4f res;
#pragma unroll
        for (int i = 0; i < 4; ++i) {
            float p;
            p = ur[i].x * vr[i].x;
            p = fmaf(ur[i].y, vr[i].y, p);
            p = fmaf(ur[i].z, vr[i].z, p);
            p = fmaf(ur[i].w, vr[i].w, p);
            p += __shfl_xor(p, 8);
            p += __shfl_xor(p, 4);
            p += __shfl_xor(p, 2);
            p += __shfl_xor(p, 1);
            res[i] = 1.0f / (1.0f + __expf(-p));
        }

        if (lane == 0) {
            __builtin_nontemporal_store(res, (v4f*)(out + eb));
        }
    } else {
        // Tail: per-edge path (E not divisible by 4).
        for (int i = 0; i < 4; ++i) {
            int e = eb + i;
            if (e >= E) break;
            int s = src[e];
            int d = dst[e];
            float4 u = ((const float4*)(h + (size_t)s * DOT_D))[lane];
            float4 v = ((const float4*)(h + (size_t)d * DOT_D))[lane];
            float p;
            p = u.x * v.x;
            p = fmaf(u.y, v.y, p);
            p = fmaf(u.z, v.z, p);
            p = fmaf(u.w, v.w, p);
            p += __shfl_xor(p, 8);
            p += __shfl_xor(p, 4);
            p += __shfl_xor(p, 2);
            p += __shfl_xor(p, 1);
            if (lane == 0) out[e] = 1.0f / (1.0f + __expf(-p));
        }
    }
}

extern "C" void kernel_launch(void* const* d_in, const int* in_sizes, int n_in,
                              void* d_out, int out_size, void* d_ws, size_t ws_size,
                              hipStream_t stream) {
    const float* h   = (const float*)d_in[0];
    const int*   src = (const int*)d_in[1];
    const int*   dst = (const int*)d_in[2];
    float*       out = (float*)d_out;

    int E = in_sizes[1];
    (void)d_ws; (void)ws_size;  // R5: deliberately workspace-free

    // 4 edges per 16-lane group -> (E+3)/4 groups, 16 threads each.
    long long groups = (E + 3) / 4;
    long long total_threads = groups * 16;
    int grid = (int)((total_threads + 255) / 256);
    dot_sigmoid_f32_mlp_kernel<<<grid, 256, 0, stream>>>(h, src, dst, out, E);
}

// Round 4
// 84.968 us; speedup vs baseline: 1.2431x; 1.2431x over previous
//
#include <hip/hip_runtime.h>
#include <hip/hip_fp16.h>
#include <math.h>

// u_dot_v + sigmoid, D=64.
// R2:  fp16 table in d_ws, 8 lanes/edge.                              [89.7 us]
// R3/4: + 4 edges/8-lane group, 8 gathers in flight.                  [84.8 us]
// R5:  ws-free f32 diagnostic: dot = 42.4 us at 141 MB HBM fetch AND at
//      ~0 HBM fetch (warm) -> NOT BW-bound; bound by scattered line rate
//      (~76 G lines/s: 3.2M lines / 42.4 us). Total 105.6 (slow container
//      + fixed reset/poison overhead).                               [105.6 us]
// R6:  back to fp16 table (1 line per row -> 1.6M lines, halves the line
//      count). Dot: 8 edges per 8-lane group -> 16 independent gathers in
//      flight per thread (2x R4's MLP). fp8/int8 rejected by arithmetic:
//      absmax would be ~0.1 >> 0.0039. Conversion kernel widened to 16 B
//      stores. Predicted dot ~23-28 us; if >=30, line-rate floor confirmed.

#define DOT_D 64

typedef int   v4i __attribute__((ext_vector_type(4)));
typedef float v4f __attribute__((ext_vector_type(4)));

// f32 -> fp16 table: 8 floats in (2x float4), 16 B out per thread.
__global__ __launch_bounds__(256) void f32_to_f16_kernel(
    const float* __restrict__ h, __half2* __restrict__ hh, int n8)
{
    int i = blockIdx.x * blockDim.x + threadIdx.x;
    if (i >= n8) return;
    float4 a = ((const float4*)h)[2 * i];
    float4 b = ((const float4*)h)[2 * i + 1];
    __half2 o[4];
    o[0] = __floats2half2_rn(a.x, a.y);
    o[1] = __floats2half2_rn(a.z, a.w);
    o[2] = __floats2half2_rn(b.x, b.y);
    o[3] = __floats2half2_rn(b.z, b.w);
    ((v4f*)hh)[i] = *(v4f*)o;   // 16 B store
}

// 8 edges per 8-lane group; 16 independent 128 B-line gathers in flight.
__global__ __launch_bounds__(256) void dot_sigmoid_f16_mlp8_kernel(
    const __half* __restrict__ h,
    const int* __restrict__ src,
    const int* __restrict__ dst,
    float* __restrict__ out,
    int E)
{
    int tid  = blockIdx.x * blockDim.x + threadIdx.x;
    int lane = tid & 7;     // 8 lanes per edge-group; 16 B/lane = 1 row line
    int g    = tid >> 3;    // group id: edges 8g .. 8g+7
    int eb   = g << 3;
    if (eb >= E) return;

    if (eb + 7 < E) {
        // Broadcast index loads: all 8 lanes read the same 32 B per list.
        v4i s0 = __builtin_nontemporal_load((const v4i*)(src + eb));
        v4i s1 = __builtin_nontemporal_load((const v4i*)(src + eb + 4));
        v4i d0 = __builtin_nontemporal_load((const v4i*)(dst + eb));
        v4i d1 = __builtin_nontemporal_load((const v4i*)(dst + eb + 4));
        int ss[8] = { s0.x, s0.y, s0.z, s0.w, s1.x, s1.y, s1.z, s1.w };
        int dd[8] = { d0.x, d0.y, d0.z, d0.w, d1.x, d1.y, d1.z, d1.w };

        // 16 independent gathers, issued back-to-back before any use.
        float4 ur[8], vr[8];
#pragma unroll
        for (int i = 0; i < 8; ++i) {
            ur[i] = ((const float4*)(h + (size_t)ss[i] * DOT_D))[lane];
            vr[i] = ((const float4*)(h + (size_t)dd[i] * DOT_D))[lane];
        }

        float res[8];
#pragma unroll
        for (int i = 0; i < 8; ++i) {
            const __half2* up = (const __half2*)&ur[i];
            const __half2* vp = (const __half2*)&vr[i];
            float p = 0.0f;
#pragma unroll
            for (int k = 0; k < 4; ++k) {
                float2 uf = __half22float2(up[k]);
                float2 vf = __half22float2(vp[k]);
                p = fmaf(uf.x, vf.x, p);
                p = fmaf(uf.y, vf.y, p);
            }
            p += __shfl_xor(p, 4);
            p += __shfl_xor(p, 2);
            p += __shfl_xor(p, 1);
            res[i] = 1.0f / (1.0f + __expf(-p));
        }

        if (lane == 0) {
            v4f a = { res[0], res[1], res[2], res[3] };
            v4f b = { res[4], res[5], res[6], res[7] };
            __builtin_nontemporal_store(a, (v4f*)(out + eb));
            __builtin_nontemporal_store(b, (v4f*)(out + eb + 4));
        }
    } else {
        // Tail: per-edge path (E not divisible by 8).
        for (int i = 0; i < 8; ++i) {
            int e = eb + i;
            if (e >= E) break;
            int s = src[e];
            int d = dst[e];
            float4 ur = ((const float4*)(h + (size_t)s * DOT_D))[lane];
            float4 vr = ((const float4*)(h + (size_t)d * DOT_D))[lane];
            const __half2* up = (const __half2*)&ur;
            const __half2* vp = (const __half2*)&vr;
            float p = 0.0f;
#pragma unroll
            for (int k = 0; k < 4; ++k) {
                float2 uf = __half22float2(up[k]);
                float2 vf = __half22float2(vp[k]);
                p = fmaf(uf.x, vf.x, p);
                p = fmaf(uf.y, vf.y, p);
            }
            p += __shfl_xor(p, 4);
            p += __shfl_xor(p, 2);
            p += __shfl_xor(p, 1);
            if (lane == 0) out[e] = 1.0f / (1.0f + __expf(-p));
        }
    }
}

// f32 fallback if d_ws is too small for the fp16 table.
__global__ __launch_bounds__(256) void dot_sigmoid_f32_kernel(
    const float* __restrict__ h,
    const int* __restrict__ src,
    const int* __restrict__ dst,
    float* __restrict__ out,
    int E)
{
    int tid  = blockIdx.x * blockDim.x + threadIdx.x;
    int lane = tid & 15;
    int e    = tid >> 4;
    if (e >= E) return;

    int s = src[e];
    int d = dst[e];
    float4 u = ((const float4*)(h + (size_t)s * DOT_D))[lane];
    float4 v = ((const float4*)(h + (size_t)d * DOT_D))[lane];
    float p = u.x * v.x + u.y * v.y + u.z * v.z + u.w * v.w;
    p += __shfl_xor(p, 8);
    p += __shfl_xor(p, 4);
    p += __shfl_xor(p, 2);
    p += __shfl_xor(p, 1);
    if (lane == 0) out[e] = 1.0f / (1.0f + __expf(-p));
}

extern "C" void kernel_launch(void* const* d_in, const int* in_sizes, int n_in,
                              void* d_out, int out_size, void* d_ws, size_t ws_size,
                              hipStream_t stream) {
    const float* h   = (const float*)d_in[0];
    const int*   src = (const int*)d_in[1];
    const int*   dst = (const int*)d_in[2];
    float*       out = (float*)d_out;

    int ND = in_sizes[0];          // N * 64
    int E  = in_sizes[1];
    size_t f16_bytes = (size_t)ND * sizeof(__half);

    if (ws_size >= f16_bytes) {
        __half* hh = (__half*)d_ws;
        int n8 = ND / 8;
        f32_to_f16_kernel<<<(n8 + 255) / 256, 256, 0, stream>>>(h, (__half2*)hh, n8);

        // 8 edges per 8-lane group -> (E+7)/8 groups, 8 threads each.
        long long groups = (E + 7) / 8;
        long long total_threads = groups * 8;
        int grid = (int)((total_threads + 255) / 256);
        dot_sigmoid_f16_mlp8_kernel<<<grid, 256, 0, stream>>>(hh, src, dst, out, E);
    } else {
        long long total_threads = (long long)E * 16;
        int grid = (int)((total_threads + 255) / 256);
        dot_sigmoid_f32_kernel<<<grid, 256, 0, stream>>>(h, src, dst, out, E);
    }
}